// Round 1
// baseline (1754.522 us; speedup 1.0000x reference)
//
#include <hip/hip_runtime.h>
#include <math.h>

#define NG 1024   // graphs per side
#define FIN 32
#define FOUT 64

// ---------------- degree: deg[dst] += 1 per edge (self-loop added later) ----
__global__ void k_degree(const int* __restrict__ ei1, const int* __restrict__ ei2,
                         int E, unsigned* __restrict__ deg, int N) {
    const int side = blockIdx.y;
    const int* ei = side ? ei2 : ei1;
    unsigned* d = deg + (size_t)side * N;
    int e = blockIdx.x * blockDim.x + threadIdx.x;
    if (e < E) atomicAdd(&d[ei[E + e]], 1u);
}

// ---------------- prep: dinv = rsqrt(deg+1); xs = x*dinv; accx = xs ---------
__global__ void k_prep(const float* __restrict__ x1, const float* __restrict__ x2,
                       const unsigned* __restrict__ deg,
                       float* __restrict__ dinv, float* __restrict__ xs,
                       float* __restrict__ accx, int N) {
    const int side = blockIdx.y;
    const float* x = side ? x2 : x1;
    int t = blockIdx.x * blockDim.x + threadIdx.x;   // n*8 + q
    int n = t >> 3, q = t & 7;
    if (n >= N) return;
    float di = rsqrtf((float)(deg[(size_t)side * N + n] + 1u));
    if (q == 0) dinv[(size_t)side * N + n] = di;
    size_t base = ((size_t)side * N + n) * FIN + q * 4;
    float4 v = *(const float4*)(x + (size_t)n * FIN + q * 4);
    v.x *= di; v.y *= di; v.z *= di; v.w *= di;
    *(float4*)(xs + base)   = v;
    *(float4*)(accx + base) = v;
}

// ---------------- scatter: accx[dst] += xs[src], 8 threads/edge -------------
__global__ void k_scatter(const int* __restrict__ ei1, const int* __restrict__ ei2,
                          int E, const float* __restrict__ xs,
                          float* __restrict__ accx, int N) {
    const int side = blockIdx.y;
    const int* ei = side ? ei2 : ei1;
    const float* xsS = xs + (size_t)side * N * FIN;
    float* ac = accx + (size_t)side * N * FIN;
    int t = blockIdx.x * blockDim.x + threadIdx.x;
    int e = t >> 3, q = t & 7;
    if (e >= E) return;
    int s = ei[e], d = ei[E + e];
    float4 v = *(const float4*)(xsS + (size_t)s * FIN + q * 4);
    float* p = ac + (size_t)d * FIN + q * 4;
    atomicAdd(p + 0, v.x);
    atomicAdd(p + 1, v.y);
    atomicAdd(p + 2, v.z);
    atomicAdd(p + 3, v.w);
}

// ---------------- node out: y = relu(dinv*(accx@W)+b); pool atomics ---------
__global__ void k_nodeout(const float* __restrict__ accx, const float* __restrict__ dinv,
                          const int* __restrict__ b1, const int* __restrict__ b2,
                          const float* __restrict__ Wc, const float* __restrict__ bc,
                          float* __restrict__ gsum, float* __restrict__ gcnt, int N) {
    __shared__ float sW[FIN * FOUT];
    __shared__ float sA[4][FIN];
    const int side = blockIdx.y;
    const int* batch = side ? b2 : b1;
    int tid = threadIdx.x;
    for (int i = tid; i < FIN * FOUT; i += 256) sW[i] = Wc[i];
    int n0 = blockIdx.x * 4;
    if (tid < 128) {
        int nn = n0 + (tid >> 5);
        int f = tid & 31;
        sA[tid >> 5][f] = (nn < N) ? accx[((size_t)side * N + nn) * FIN + f] : 0.f;
    }
    __syncthreads();
    int local = tid >> 6;        // node within block, 0..3
    int f = tid & 63;            // output feature
    int n = n0 + local;
    if (n < N) {
        float acc = 0.f;
#pragma unroll
        for (int i = 0; i < FIN; i++) acc += sA[local][i] * sW[i * FOUT + f];
        float y = fmaxf(dinv[(size_t)side * N + n] * acc + bc[f], 0.f);
        int b = batch[n];
        atomicAdd(&gsum[(((size_t)side * NG) + b) * FOUT + f], y);
        if (f == 0) atomicAdd(&gcnt[(size_t)side * NG + b], 1.f);
    }
}

// ---------------- MLP head: 128->64->32->16->1 + sigmoid --------------------
__global__ void k_mlp(const float* __restrict__ gsum, const float* __restrict__ gcnt,
                      const float* __restrict__ W1, const float* __restrict__ bb1,
                      const float* __restrict__ W2, const float* __restrict__ bb2,
                      const float* __restrict__ W3, const float* __restrict__ bb3,
                      const float* __restrict__ W4, const float* __restrict__ bb4,
                      float* __restrict__ out) {
    __shared__ float h[128], h1[64], h2[32], h3[16];
    int g = blockIdx.x, tid = threadIdx.x;
    int side = tid >> 6, f = tid & 63;
    float c = fmaxf(gcnt[(size_t)side * NG + g], 1.f);
    h[tid] = gsum[(((size_t)side * NG) + g) * FOUT + f] / c;
    __syncthreads();
    if (tid < 64) {
        float a = bb1[tid];
#pragma unroll 8
        for (int i = 0; i < 128; i++) a += h[i] * W1[i * 64 + tid];
        h1[tid] = fmaxf(a, 0.f);
    }
    __syncthreads();
    if (tid < 32) {
        float a = bb2[tid];
#pragma unroll 8
        for (int i = 0; i < 64; i++) a += h1[i] * W2[i * 32 + tid];
        h2[tid] = fmaxf(a, 0.f);
    }
    __syncthreads();
    if (tid < 16) {
        float a = bb3[tid];
#pragma unroll 8
        for (int i = 0; i < 32; i++) a += h2[i] * W3[i * 16 + tid];
        h3[tid] = fmaxf(a, 0.f);
    }
    __syncthreads();
    if (tid == 0) {
        float a = bb4[0];
#pragma unroll
        for (int i = 0; i < 16; i++) a += h3[i] * W4[i];
        out[g] = 1.f / (1.f + expf(-a));
    }
}

extern "C" void kernel_launch(void* const* d_in, const int* in_sizes, int n_in,
                              void* d_out, int out_size, void* d_ws, size_t ws_size,
                              hipStream_t stream) {
    const float* x1  = (const float*)d_in[0];
    const int*   ei1 = (const int*)d_in[1];
    const int*   bt1 = (const int*)d_in[2];
    const float* x2  = (const float*)d_in[3];
    const int*   ei2 = (const int*)d_in[4];
    const int*   bt2 = (const int*)d_in[5];
    const float* Wc  = (const float*)d_in[6];
    const float* bc  = (const float*)d_in[7];
    const float* W1  = (const float*)d_in[8];
    const float* bb1 = (const float*)d_in[9];
    const float* W2  = (const float*)d_in[10];
    const float* bb2 = (const float*)d_in[11];
    const float* W3  = (const float*)d_in[12];
    const float* bb3 = (const float*)d_in[13];
    const float* W4  = (const float*)d_in[14];
    const float* bb4 = (const float*)d_in[15];

    const int N = in_sizes[0] / FIN;     // 100000
    const int E = in_sizes[1] / 2;       // 1600000

    // workspace layout (floats):
    // [0, 2N)                : deg (u32, both sides)          -- zeroed
    // [2N, 2N+2*G*64)        : gsum                            -- zeroed
    // [.., +2*G)             : gcnt                            -- zeroed
    // [.., +2N)              : dinv
    // [.., +64N)             : xs
    // [.., +64N)             : accx
    float* ws = (float*)d_ws;
    unsigned* deg = (unsigned*)ws;
    float* gsum = ws + 2 * (size_t)N;
    float* gcnt = gsum + 2 * (size_t)NG * FOUT;
    float* dinv = gcnt + 2 * (size_t)NG;
    float* xs   = dinv + 2 * (size_t)N;
    float* accx = xs + 2 * (size_t)N * FIN;

    size_t zbytes = (2 * (size_t)N + 2 * (size_t)NG * FOUT + 2 * (size_t)NG) * sizeof(float);
    hipMemsetAsync(d_ws, 0, zbytes, stream);

    dim3 blk(256);
    k_degree<<<dim3((E + 255) / 256, 2), blk, 0, stream>>>(ei1, ei2, E, deg, N);
    k_prep<<<dim3((N * 8 + 255) / 256, 2), blk, 0, stream>>>(x1, x2, deg, dinv, xs, accx, N);
    {
        long long tt = (long long)E * 8;
        k_scatter<<<dim3((unsigned)((tt + 255) / 256), 2), blk, 0, stream>>>(ei1, ei2, E, xs, accx, N);
    }
    k_nodeout<<<dim3((N + 3) / 4, 2), blk, 0, stream>>>(accx, dinv, bt1, bt2, Wc, bc, gsum, gcnt, N);
    k_mlp<<<NG, 128, 0, stream>>>(gsum, gcnt, W1, bb1, W2, bb2, W3, bb3, W4, bb4, (float*)d_out);
}

// Round 6
// 846.742 us; speedup vs baseline: 2.0721x; 2.0721x over previous
//
#include <hip/hip_runtime.h>
#include <math.h>

#define NG 1024   // graphs per side
#define FIN 32
#define FOUT 64

// ---------------- degree: deg[dst] += 1 per edge (self-loop added later) ----
__global__ void k_degree(const int* __restrict__ ei1, const int* __restrict__ ei2,
                         int E, unsigned* __restrict__ deg, int N) {
    const int side = blockIdx.y;
    const int* ei = side ? ei2 : ei1;
    unsigned* d = deg + (size_t)side * N;
    int e = blockIdx.x * blockDim.x + threadIdx.x;
    if (e < E) atomicAdd(&d[ei[E + e]], 1u);
}

// ---------------- rowstart: chunk allocation via wave-aggregated atomic -----
// Rows get contiguous [rowstart, rowstart+deg) ranges in ARBITRARY order —
// legal for CSR since only per-row consistency matters. One atomic per wave.
__global__ void k_rowstart(const unsigned* __restrict__ deg,
                           unsigned* __restrict__ rowstart,
                           unsigned* __restrict__ cursor,
                           unsigned* __restrict__ gcur, int N) {
    const int side = blockIdx.y;
    int n = blockIdx.x * blockDim.x + threadIdx.x;
    unsigned d = (n < N) ? deg[(size_t)side * N + n] : 0u;
    unsigned lane = threadIdx.x & 63;
    // inclusive wave scan
    unsigned v = d;
    for (int off = 1; off < 64; off <<= 1) {
        unsigned u = __shfl_up(v, off);
        if (lane >= off) v += u;
    }
    unsigned total = __shfl(v, 63);
    unsigned excl = v - d;
    unsigned base = 0;
    if (lane == 63) base = atomicAdd(&gcur[side], total);
    base = __shfl(base, 63);
    if (n < N) {
        unsigned r = base + excl;
        rowstart[(size_t)side * N + n] = r;
        cursor[(size_t)side * N + n] = r;
    }
}

// ---------------- prep: dinv = rsqrt(deg+1); xs = x*dinv --------------------
__global__ void k_prep(const float* __restrict__ x1, const float* __restrict__ x2,
                       const unsigned* __restrict__ deg,
                       float* __restrict__ dinv, float* __restrict__ xs, int N) {
    const int side = blockIdx.y;
    const float* x = side ? x2 : x1;
    int t = blockIdx.x * blockDim.x + threadIdx.x;   // n*8 + q
    int n = t >> 3, q = t & 7;
    if (n >= N) return;
    float di = rsqrtf((float)(deg[(size_t)side * N + n] + 1u));
    if (q == 0) dinv[(size_t)side * N + n] = di;
    size_t base = ((size_t)side * N + n) * FIN + q * 4;
    float4 v = *(const float4*)(x + (size_t)n * FIN + q * 4);
    v.x *= di; v.y *= di; v.z *= di; v.w *= di;
    *(float4*)(xs + base) = v;
}

// ---------------- fill CSR: csr[cursor[dst]++] = src ------------------------
__global__ void k_fill(const int* __restrict__ ei1, const int* __restrict__ ei2,
                       int E, unsigned* __restrict__ cursor,
                       unsigned* __restrict__ csr, int N) {
    const int side = blockIdx.y;
    const int* ei = side ? ei2 : ei1;
    int e = blockIdx.x * blockDim.x + threadIdx.x;
    if (e >= E) return;
    int s = ei[e], d = ei[E + e];
    unsigned pos = atomicAdd(&cursor[(size_t)side * N + d], 1u);
    csr[(size_t)side * E + pos] = (unsigned)s;
}

// ---------------- gather: accx[n] = xs[n] + sum_{s in row(n)} xs[s] ---------
// 8 threads per node; each owns one float4 of the 32-f row.
// cursor (post-fill) == row end.
__global__ void k_gather(const unsigned* __restrict__ rowstart,
                         const unsigned* __restrict__ rowend,
                         const unsigned* __restrict__ csr,
                         const float* __restrict__ xs,
                         float* __restrict__ accx, int N, int E) {
    const int side = blockIdx.y;
    int t = blockIdx.x * blockDim.x + threadIdx.x;
    int n = t >> 3, q = t & 7;
    if (n >= N) return;
    const unsigned* cs = csr + (size_t)side * E;
    const float* xsS = xs + (size_t)side * N * FIN;
    size_t nbase = ((size_t)side * N + n) * FIN + q * 4;
    float4 acc = *(const float4*)(xs + nbase);   // self-loop term (already *dinv)
    unsigned j = rowstart[(size_t)side * N + n];
    unsigned re = rowend[(size_t)side * N + n];
    // 2-wide unroll for MLP (two independent idx loads + two gathers in flight)
    for (; j + 1 < re; j += 2) {
        unsigned s0 = cs[j], s1 = cs[j + 1];
        float4 a0 = *(const float4*)(xsS + (size_t)s0 * FIN + q * 4);
        float4 a1 = *(const float4*)(xsS + (size_t)s1 * FIN + q * 4);
        acc.x += a0.x; acc.y += a0.y; acc.z += a0.z; acc.w += a0.w;
        acc.x += a1.x; acc.y += a1.y; acc.z += a1.z; acc.w += a1.w;
    }
    if (j < re) {
        unsigned s0 = cs[j];
        float4 a0 = *(const float4*)(xsS + (size_t)s0 * FIN + q * 4);
        acc.x += a0.x; acc.y += a0.y; acc.z += a0.z; acc.w += a0.w;
    }
    *(float4*)(accx + nbase) = acc;
}

// ---------------- node out: y = relu(dinv*(accx@W)+b); pool atomics ---------
__global__ void k_nodeout(const float* __restrict__ accx, const float* __restrict__ dinv,
                          const int* __restrict__ b1, const int* __restrict__ b2,
                          const float* __restrict__ Wc, const float* __restrict__ bc,
                          float* __restrict__ gsum, float* __restrict__ gcnt, int N) {
    __shared__ float sW[FIN * FOUT];
    __shared__ float sA[4][FIN];
    const int side = blockIdx.y;
    const int* batch = side ? b2 : b1;
    int tid = threadIdx.x;
    for (int i = tid; i < FIN * FOUT; i += 256) sW[i] = Wc[i];
    int n0 = blockIdx.x * 4;
    if (tid < 128) {
        int nn = n0 + (tid >> 5);
        int f = tid & 31;
        sA[tid >> 5][f] = (nn < N) ? accx[((size_t)side * N + nn) * FIN + f] : 0.f;
    }
    __syncthreads();
    int local = tid >> 6;        // node within block, 0..3
    int f = tid & 63;            // output feature
    int n = n0 + local;
    if (n < N) {
        float acc = 0.f;
#pragma unroll
        for (int i = 0; i < FIN; i++) acc += sA[local][i] * sW[i * FOUT + f];
        float y = fmaxf(dinv[(size_t)side * N + n] * acc + bc[f], 0.f);
        int b = batch[n];
        atomicAdd(&gsum[(((size_t)side * NG) + b) * FOUT + f], y);
        if (f == 0) atomicAdd(&gcnt[(size_t)side * NG + b], 1.f);
    }
}

// ---------------- MLP head: 128->64->32->16->1 + sigmoid --------------------
__global__ void k_mlp(const float* __restrict__ gsum, const float* __restrict__ gcnt,
                      const float* __restrict__ W1, const float* __restrict__ bb1,
                      const float* __restrict__ W2, const float* __restrict__ bb2,
                      const float* __restrict__ W3, const float* __restrict__ bb3,
                      const float* __restrict__ W4, const float* __restrict__ bb4,
                      float* __restrict__ out) {
    __shared__ float h[128], h1[64], h2[32], h3[16];
    int g = blockIdx.x, tid = threadIdx.x;
    int side = tid >> 6, f = tid & 63;
    float c = fmaxf(gcnt[(size_t)side * NG + g], 1.f);
    h[tid] = gsum[(((size_t)side * NG) + g) * FOUT + f] / c;
    __syncthreads();
    if (tid < 64) {
        float a = bb1[tid];
#pragma unroll 8
        for (int i = 0; i < 128; i++) a += h[i] * W1[i * 64 + tid];
        h1[tid] = fmaxf(a, 0.f);
    }
    __syncthreads();
    if (tid < 32) {
        float a = bb2[tid];
#pragma unroll 8
        for (int i = 0; i < 64; i++) a += h1[i] * W2[i * 32 + tid];
        h2[tid] = fmaxf(a, 0.f);
    }
    __syncthreads();
    if (tid < 16) {
        float a = bb3[tid];
#pragma unroll 8
        for (int i = 0; i < 32; i++) a += h2[i] * W3[i * 16 + tid];
        h3[tid] = fmaxf(a, 0.f);
    }
    __syncthreads();
    if (tid == 0) {
        float a = bb4[0];
#pragma unroll
        for (int i = 0; i < 16; i++) a += h3[i] * W4[i];
        out[g] = 1.f / (1.f + expf(-a));
    }
}

extern "C" void kernel_launch(void* const* d_in, const int* in_sizes, int n_in,
                              void* d_out, int out_size, void* d_ws, size_t ws_size,
                              hipStream_t stream) {
    const float* x1  = (const float*)d_in[0];
    const int*   ei1 = (const int*)d_in[1];
    const int*   bt1 = (const int*)d_in[2];
    const float* x2  = (const float*)d_in[3];
    const int*   ei2 = (const int*)d_in[4];
    const int*   bt2 = (const int*)d_in[5];
    const float* Wc  = (const float*)d_in[6];
    const float* bc  = (const float*)d_in[7];
    const float* W1  = (const float*)d_in[8];
    const float* bb1 = (const float*)d_in[9];
    const float* W2  = (const float*)d_in[10];
    const float* bb2 = (const float*)d_in[11];
    const float* W3  = (const float*)d_in[12];
    const float* bb3 = (const float*)d_in[13];
    const float* W4  = (const float*)d_in[14];
    const float* bb4 = (const float*)d_in[15];

    const int N = in_sizes[0] / FIN;     // 100000
    const int E = in_sizes[1] / 2;       // 1600000

    // workspace layout (4-byte units):
    // deg(2N) | gcur(16) | gsum(2*NG*64) | gcnt(2*NG)   <-- zeroed
    // dinv(2N) | xs(64N) | accx(64N) | rowstart(2N) | cursor(2N) | csr(2E)
    float* ws = (float*)d_ws;
    unsigned* deg = (unsigned*)ws;
    unsigned* gcur = deg + 2 * (size_t)N;
    float* gsum = (float*)(gcur + 16);
    float* gcnt = gsum + 2 * (size_t)NG * FOUT;
    float* dinv = gcnt + 2 * (size_t)NG;
    float* xs   = dinv + 2 * (size_t)N;
    float* accx = xs + 2 * (size_t)N * FIN;
    unsigned* rowstart = (unsigned*)(accx + 2 * (size_t)N * FIN);
    unsigned* cursor = rowstart + 2 * (size_t)N;
    unsigned* csr = cursor + 2 * (size_t)N;

    size_t zbytes = (2 * (size_t)N + 16 + 2 * (size_t)NG * FOUT + 2 * (size_t)NG) * 4;
    hipMemsetAsync(d_ws, 0, zbytes, stream);

    dim3 blk(256);
    k_degree<<<dim3((E + 255) / 256, 2), blk, 0, stream>>>(ei1, ei2, E, deg, N);
    k_rowstart<<<dim3((N + 255) / 256, 2), blk, 0, stream>>>(deg, rowstart, cursor, gcur, N);
    k_prep<<<dim3((N * 8 + 255) / 256, 2), blk, 0, stream>>>(x1, x2, deg, dinv, xs, N);
    k_fill<<<dim3((E + 255) / 256, 2), blk, 0, stream>>>(ei1, ei2, E, cursor, csr, N);
    k_gather<<<dim3((N * 8 + 255) / 256, 2), blk, 0, stream>>>(rowstart, cursor, csr, xs, accx, N, E);
    k_nodeout<<<dim3((N + 3) / 4, 2), blk, 0, stream>>>(accx, dinv, bt1, bt2, Wc, bc, gsum, gcnt, N);
    k_mlp<<<NG, 128, 0, stream>>>(gsum, gcnt, W1, bb1, W2, bb2, W3, bb3, W4, bb4, (float*)d_out);
}